// Round 1
// 256.156 us; speedup vs baseline: 1.0105x; 1.0105x over previous
//
#include <hip/hip_runtime.h>
#include <hip/hip_bf16.h>

// Dynamic per-tensor symmetric int8 quantized GEMM (AQT-style).
//   bound = max(absmax(x), 1e-6); scale = 127/bound
//   q = clip(rint(x*scale), -127, 127)  (int8)
//   out = (q_lhs @ q_rhs) * bound_l*bound_r/127^2   (fp32)
//
// R4: GEMM rewritten to the 256x256 deep-pipelined structure (T3+T4+T5):
//   - BM=BN=256, BK=128, 8 waves (2Mx4N), 512 threads, 1 block/CU
//   - double-buffered 128KB LDS, global_load_lds staging w/ chunk swizzle
//     v(r)=(r^(r>>3))&7 applied on the GLOBAL source side (dst linear)
//   - raw s_barrier + COUNTED s_waitcnt vmcnt(8) (never 0 in main loop):
//     tile t+2's loads stay in flight across barriers while computing t
//   - s_setprio(1) around each 8-MFMA cluster
// absmax/quant kernels unchanged from R3.

typedef int v4i __attribute__((ext_vector_type(4)));
typedef int v16i __attribute__((ext_vector_type(16)));

#define MAT_N 4096

__device__ __forceinline__ void async_copy16(const void* g, void* l) {
    __builtin_amdgcn_global_load_lds(
        (const __attribute__((address_space(1))) void*)g,
        (__attribute__((address_space(3))) void*)l,
        16, 0, 0);
}

__device__ __forceinline__ unsigned uabs_bits(float f) {
    return __float_as_uint(f) & 0x7fffffffu;
}

// ---- absmax partials: blocks [0,512) lhs, [512,1024) rhs; pmax[b] plain store
__global__ __launch_bounds__(256) void absmax_partial_kernel(
    const float4* __restrict__ lhs, const float4* __restrict__ rhs,
    unsigned* __restrict__ pmax) {
    const int b = blockIdx.x;
    const float4* x = (b < 512) ? lhs : rhs;
    const float4* p = x + (size_t)(b & 511) * 8192;
    unsigned m0 = 0, m1 = 0, m2 = 0, m3 = 0;
#pragma unroll 8
    for (int u = 0; u < 32; u++) {
        float4 v = p[u * 256 + threadIdx.x];
        m0 = max(m0, uabs_bits(v.x));
        m1 = max(m1, uabs_bits(v.y));
        m2 = max(m2, uabs_bits(v.z));
        m3 = max(m3, uabs_bits(v.w));
    }
    unsigned m = max(max(m0, m1), max(m2, m3));
#pragma unroll
    for (int off = 32; off > 0; off >>= 1)
        m = max(m, (unsigned)__shfl_down(m, off, 64));
    __shared__ unsigned sm[4];
    if ((threadIdx.x & 63) == 0) sm[threadIdx.x >> 6] = m;
    __syncthreads();
    if (threadIdx.x == 0)
        pmax[b] = max(max(sm[0], sm[1]), max(sm[2], sm[3]));
}

// ---- fused quantize: blocks [0,4096) lhs passthrough; [4096,8192) rhs transpose
__global__ __launch_bounds__(256) void quant_fused_kernel(
    const float* __restrict__ lhs, const float* __restrict__ rhs,
    unsigned char* __restrict__ qA, signed char* __restrict__ qBT,
    const unsigned* __restrict__ pmax) {
    const int N = MAT_N;
    const int t = threadIdx.x;
    int b = blockIdx.x;
    __shared__ __align__(16) signed char smT[64 * 80];  // [n][k], LDSP=80
    __shared__ unsigned red[4];
    __shared__ float s_sh;

    // Reduce this tensor's 512 partials -> scale (L2-hot, ~2KB)
    const int slot0 = (b < 4096) ? 0 : 512;
    unsigned mm = max(pmax[slot0 + t], pmax[slot0 + 256 + t]);
#pragma unroll
    for (int off = 32; off > 0; off >>= 1)
        mm = max(mm, (unsigned)__shfl_down(mm, off, 64));
    if ((t & 63) == 0) red[t >> 6] = mm;
    __syncthreads();
    if (t == 0) {
        unsigned f = max(max(red[0], red[1]), max(red[2], red[3]));
        s_sh = 127.0f / fmaxf(__uint_as_float(f), 1e-6f);
    }
    __syncthreads();
    const float s = s_sh;

    if (b < 4096) {
        const float4* x4 = (const float4*)lhs;
        unsigned* q4 = (unsigned*)qA;
        const int base4 = b * 1024;
#pragma unroll
        for (int u = 0; u < 4; u++) {
            int idx = base4 + u * 256 + t;
            float4 v = x4[idx];
            int a = min(127, max(-127, (int)rintf(v.x * s)));
            int bq = min(127, max(-127, (int)rintf(v.y * s)));
            int c = min(127, max(-127, (int)rintf(v.z * s)));
            int d = min(127, max(-127, (int)rintf(v.w * s)));
            q4[idx] = (unsigned)(a & 0xff) | ((unsigned)(bq & 0xff) << 8) |
                      ((unsigned)(c & 0xff) << 16) | ((unsigned)(d & 0xff) << 24);
        }
    } else {
        b -= 4096;
        const int n0 = (b & 63) * 64;   // column origin (floats)
        const int k0 = (b >> 6) * 64;   // row origin
        const int mk = t >> 4;          // 0..15 -> k = 4*mk
        const int mn = t & 15;          // 0..15 -> n = 4*mn
        const float4* x4 = (const float4*)rhs;

        unsigned w[4];
#pragma unroll
        for (int i = 0; i < 4; i++) {
            float4 v = x4[(size_t)(k0 + 4 * mk + i) * (N / 4) + (n0 >> 2) + mn];
            int a = min(127, max(-127, (int)rintf(v.x * s)));
            int bq = min(127, max(-127, (int)rintf(v.y * s)));
            int c = min(127, max(-127, (int)rintf(v.z * s)));
            int d = min(127, max(-127, (int)rintf(v.w * s)));
            w[i] = (unsigned)(a & 0xff) | ((unsigned)(bq & 0xff) << 8) |
                   ((unsigned)(c & 0xff) << 16) | ((unsigned)(d & 0xff) << 24);
        }
        // 4x4 byte transpose in registers
#pragma unroll
        for (int j = 0; j < 4; j++) {
            unsigned selj = (unsigned)j | ((unsigned)(4 + j) << 8) |
                            ((unsigned)j << 16) | ((unsigned)(4 + j) << 24);
            unsigned p01 = __builtin_amdgcn_perm(w[1], w[0], selj);
            unsigned p23 = __builtin_amdgcn_perm(w[3], w[2], selj);
            unsigned uj = __builtin_amdgcn_perm(p23, p01, 0x05040100u);
            *(unsigned*)(smT + (4 * mn + j) * 80 + 4 * mk) = uj;
        }
        __syncthreads();
        const int nr = t >> 2;
        const int kq = (t & 3) * 16;
        int4 val = *(const int4*)(smT + nr * 80 + kq);
        *(int4*)(qBT + (size_t)(n0 + nr) * N + k0 + kq) = val;
    }
}

// ---- int8 MFMA GEMM: C = A(MxK) * BT(NxK)^T
// 256x256 tile, BK=128, mfma_i32_32x32x32_i8, 8 waves (2Mx4N), wave tile
// 128x64 = 4x2 of 32x32. Double-buffered LDS (2x32KB per operand),
// counted vmcnt pipeline: tile t+1 always fully staged, tile t+2 in flight.
// LDS chunk swizzle v(r)=(r^(r>>3))&7: global chunk (r,q) -> LDS slot
// (r, q^v(r)); global_load_lds dst stays linear (rule: swizzle the source).
__global__ __launch_bounds__(512, 2) void gemm_i8_kernel(
    const signed char* __restrict__ A, const signed char* __restrict__ BT,
    float* __restrict__ C, const unsigned* __restrict__ pmax) {
    const int N = MAT_N;
    __shared__ __align__(16) signed char As[2][256 * 128];
    __shared__ __align__(16) signed char Bs[2][256 * 128];
    __shared__ unsigned redl[8], redr[8];

    const int tid = threadIdx.x;
    const int wave = tid >> 6;   // 0..7
    const int lane = tid & 63;
    const int m32 = lane & 31;   // row/col within a 32-tile
    const int h = lane >> 5;     // k-half selector
    const int wm = wave >> 2;    // 0..1 -> 128-row half of the M-tile
    const int wn = wave & 3;     // 0..3 -> 64-col quarter of the N-tile

    // XCD-aware swizzle: 256 blocks -> 16x16 grid; XCD x owns a 4x8 rect
    // (blockIdx round-robins across the 8 XCDs -> compact L2 working sets).
    const int bid = blockIdx.x;
    const int xcd = bid & 7;
    const int bi = bid >> 3;                 // 0..31 within XCD
    const int by = (xcd >> 1) * 4 + (bi >> 3);
    const int bx = (xcd & 1) * 8 + (bi & 7);
    const int brow = by * 256;
    const int bcol = bx * 256;

    v16i acc[4][2] = {};

    // Staging: 2048 16B-chunks per 256x128 tile; 4 chunks/thread/operand.
    // LDS slot c=(r=c>>3, q'=c&7) receives global chunk q = q' ^ v(r).
    int gaoff[4], gboff[4], lofs[4];
#pragma unroll
    for (int u = 0; u < 4; u++) {
        int c = tid + 512 * u;
        int r = c >> 3;
        int q = (c & 7) ^ ((r ^ (r >> 3)) & 7);
        gaoff[u] = (brow + r) * N + q * 16;
        gboff[u] = (bcol + r) * N + q * 16;
        lofs[u] = c * 16;
    }

    // Fragment row bases + swizzle keys (k-invariant)
    int arow[4], av[4];
#pragma unroll
    for (int mi = 0; mi < 4; mi++) {
        int r = wm * 128 + mi * 32 + m32;
        arow[mi] = r * 128;
        av[mi] = (r ^ (r >> 3)) & 7;
    }
    int bro[2], bv[2];
#pragma unroll
    for (int nj = 0; nj < 2; nj++) {
        int r = wn * 64 + nj * 32 + m32;
        bro[nj] = r * 128;
        bv[nj] = (r ^ (r >> 3)) & 7;
    }

    auto stage = [&](int buf, int koff) {
#pragma unroll
        for (int u = 0; u < 4; u++)
            async_copy16(A + gaoff[u] + koff, &As[buf][lofs[u]]);
#pragma unroll
        for (int u = 0; u < 4; u++)
            async_copy16(BT + gboff[u] + koff, &Bs[buf][lofs[u]]);
    };

    // One K=32 slice: 6x ds_read_b128 + 8x mfma (compiler interleaves slices)
    auto slice = [&](const signed char* as_, const signed char* bs_, int s) {
        v4i af[4], bf[2];
        const int q = 2 * s + h;  // 16B chunk of this lane's k-slice
#pragma unroll
        for (int mi = 0; mi < 4; mi++)
            af[mi] = *(const v4i*)(as_ + arow[mi] + ((q ^ av[mi]) << 4));
#pragma unroll
        for (int nj = 0; nj < 2; nj++)
            bf[nj] = *(const v4i*)(bs_ + bro[nj] + ((q ^ bv[nj]) << 4));
        __builtin_amdgcn_s_setprio(1);
#pragma unroll
        for (int mi = 0; mi < 4; mi++)
#pragma unroll
            for (int nj = 0; nj < 2; nj++)
                acc[mi][nj] = __builtin_amdgcn_mfma_i32_32x32x32_i8(
                    af[mi], bf[nj], acc[mi][nj], 0, 0, 0);
        __builtin_amdgcn_s_setprio(0);
    };

    // Prologue: stage tiles 0,1; wait tile 0 only (tile 1 stays in flight).
    stage(0, 0);
    stage(1, 128);
    asm volatile("s_waitcnt vmcnt(8)" ::: "memory");
    __builtin_amdgcn_s_barrier();
    __builtin_amdgcn_sched_barrier(0);

    // Main loop: tiles 0..29. Invariant at top of iter t:
    //   buf[t&1] holds tile t (landed+barriered), tile t+1's loads in flight.
    for (int t = 0; t < 30; ++t) {
        const signed char* as_ = As[t & 1];
        const signed char* bs_ = Bs[t & 1];
        slice(as_, bs_, 0);
        slice(as_, bs_, 1);
        slice(as_, bs_, 2);
        slice(as_, bs_, 3);
        // Every ds_read above was consumed by an MFMA -> this wave is done
        // with buf[t&1]; barrier makes that true for all waves.
        __builtin_amdgcn_s_barrier();
        __builtin_amdgcn_sched_barrier(0);
        stage(t & 1, (t + 2) * 128);  // refill freed buffer (issue only)
        // Wait for tile t+1 (issued one full iteration ago -> ~free);
        // tile t+2's 8 loads remain in flight across the barrier.
        asm volatile("s_waitcnt vmcnt(8)" ::: "memory");
        __builtin_amdgcn_s_barrier();
        __builtin_amdgcn_sched_barrier(0);
    }
    // Tile 30 (buf0): no more staging; then drain for tile 31.
    {
        const signed char* as_ = As[0];
        const signed char* bs_ = Bs[0];
        slice(as_, bs_, 0);
        slice(as_, bs_, 1);
        slice(as_, bs_, 2);
        slice(as_, bs_, 3);
        asm volatile("s_waitcnt vmcnt(0)" ::: "memory");
        __builtin_amdgcn_s_barrier();
        __builtin_amdgcn_sched_barrier(0);
    }
    // Tile 31 (buf1)
    {
        const signed char* as_ = As[1];
        const signed char* bs_ = Bs[1];
        slice(as_, bs_, 0);
        slice(as_, bs_, 1);
        slice(as_, bs_, 2);
        slice(as_, bs_, 3);
    }

    // Dequant scales from the 1024 partials (512 lhs, 512 rhs)
    unsigned ml = pmax[tid];
    unsigned mr = pmax[512 + tid];
#pragma unroll
    for (int off = 32; off > 0; off >>= 1) {
        ml = max(ml, (unsigned)__shfl_down(ml, off, 64));
        mr = max(mr, (unsigned)__shfl_down(mr, off, 64));
    }
    if (lane == 0) { redl[wave] = ml; redr[wave] = mr; }
    __syncthreads();
    unsigned fl = redl[0], fr = redr[0];
#pragma unroll
    for (int k = 1; k < 8; k++) {
        fl = max(fl, redl[k]);
        fr = max(fr, redr[k]);
    }
    const float bl = fmaxf(__uint_as_float(fl), 1e-6f);
    const float br = fmaxf(__uint_as_float(fr), 1e-6f);
    const float dq = bl * br * (1.0f / (127.0f * 127.0f));

    // C/D layout (32x32): col = lane&31, row = (reg&3) + 8*(reg>>2) + 4*h
#pragma unroll
    for (int mi = 0; mi < 4; mi++)
#pragma unroll
        for (int nj = 0; nj < 2; nj++) {
            const int col = bcol + wn * 64 + nj * 32 + m32;
#pragma unroll
            for (int reg = 0; reg < 16; reg++) {
                const int row =
                    brow + wm * 128 + mi * 32 + (reg & 3) + 8 * (reg >> 2) + 4 * h;
                C[(size_t)row * N + col] = (float)acc[mi][nj][reg] * dq;
            }
        }
}

extern "C" void kernel_launch(void* const* d_in, const int* in_sizes, int n_in,
                              void* d_out, int out_size, void* d_ws, size_t ws_size,
                              hipStream_t stream) {
    const float* lhs = (const float*)d_in[0];
    const float* rhs = (const float*)d_in[1];
    float* out = (float*)d_out;

    unsigned* pmax = (unsigned*)d_ws;  // 1024 partials (all written each call)
    signed char* qA = (signed char*)d_ws + 8192;
    signed char* qBT = qA + (size_t)MAT_N * MAT_N;

    absmax_partial_kernel<<<1024, 256, 0, stream>>>(
        (const float4*)lhs, (const float4*)rhs, pmax);
    quant_fused_kernel<<<8192, 256, 0, stream>>>(
        lhs, rhs, (unsigned char*)qA, qBT, pmax);
    gemm_i8_kernel<<<256, 512, 0, stream>>>(qA, qBT, out, pmax);
}